// Round 2
// baseline (533.023 us; speedup 1.0000x reference)
//
#include <hip/hip_runtime.h>
#include <hip/hip_bf16.h>
#include <stdint.h>

#define N 8192
#define D 128
#define NCHUNK 16
#define CHUNK (N / NCHUNK)      // 512 cols per chunk
#define RT 64                   // rows per block (4 waves x 16)
#define CT 64                   // cols per LDS tile
#define NTILES (CHUNK / CT)     // 8

typedef short bf16x8 __attribute__((ext_vector_type(8)));
typedef float f32x4 __attribute__((ext_vector_type(4)));
typedef unsigned int uint32;

// ---- workspace layout (bytes) ----
#define OFF_ACC   0u                         // [0] float S_sum, [4] uint32 C_count
#define OFF_SQ2   1024u                      // 8192 floats
#define OFF_M     40960u                     // NCHUNK*N floats
#define OFF_L     (OFF_M + NCHUNK * N * 4u)
#define OFF_S     (OFF_L + NCHUNK * N * 4u)
#define OFF_F1    (OFF_S + NCHUNK * N * 4u)  // feat1 bf16 (N*D ushort)
#define OFF_F2    (OFF_F1 + N * D * 2u)      // feat2 bf16

// Convert feats to bf16; compute sq2[j] = ||feat2_j||^2.
// 256 blocks x 256 threads (was 16384 one-wave blocks: dispatch-bound).
__global__ __launch_bounds__(256)
void prep_kernel(const float* __restrict__ f1, const float* __restrict__ f2,
                 unsigned short* __restrict__ f1b, unsigned short* __restrict__ f2b,
                 float* __restrict__ sq2) {
    const int w    = blockIdx.x * 4 + (threadIdx.x >> 6);  // 0..1023
    const int lane = threadIdx.x & 63;
    for (int row = w; row < N; row += 1024) {
        float a0 = f1[row * D + lane];
        float a1 = f1[row * D + 64 + lane];
        float b0 = f2[row * D + lane];
        float b1 = f2[row * D + 64 + lane];
        __hip_bfloat16 t;
        t = __float2bfloat16(a0); f1b[row * D + lane]      = *(unsigned short*)&t;
        t = __float2bfloat16(a1); f1b[row * D + 64 + lane] = *(unsigned short*)&t;
        t = __float2bfloat16(b0); f2b[row * D + lane]      = *(unsigned short*)&t;
        t = __float2bfloat16(b1); f2b[row * D + 64 + lane] = *(unsigned short*)&t;
        float ss = b0 * b0 + b1 * b1;
        #pragma unroll
        for (int off = 32; off > 0; off >>= 1) ss += __shfl_xor(ss, off);
        if (lane == 0) sq2[row] = ss;
    }
}

// Fused GEMM + online softmax + masked accumulation.
// Block = (rowtile, chunk): rows [rowtile*64, +64), cols [chunk*512, +512).
// Column permutation: LDS B-position q holds global col c(q)=4*(q&15)+(q>>4),
// so acc[cf] lane lo holds global col 4*lo+cf -> mask loads become int4.
// Softmax row-sums / maxes are permutation-invariant, so this is free.
__global__ __launch_bounds__(256, 8)   // force VGPR<=64 -> 8 blocks/CU
void main_kernel(const unsigned short* __restrict__ f1b,
                 const unsigned short* __restrict__ f2b,
                 const float* __restrict__ sq2,
                 const int* __restrict__ simi,
                 float* __restrict__ pm, float* __restrict__ pl, float* __restrict__ ps,
                 uint32* __restrict__ cnt_acc) {
    __shared__ unsigned short ldsB[CT * D];  // 16 KB, XOR-swizzled
    __shared__ float ldsSq[CHUNK];           // 2 KB, stored in PERMUTED order per tile

    const int tid  = threadIdx.x;
    const int wave = tid >> 6;
    const int lane = tid & 63;
    const int lo   = lane & 15;
    const int hi   = lane >> 4;

    const int rowtile = blockIdx.x;       // 0..127
    const int chunk   = blockIdx.y;       // 0..15
    const int rbase   = rowtile * RT + wave * 16;
    const int cbase0  = chunk * CHUNK;

    // stage sq2 for this chunk (natural order; read with permuted index later)
    for (int i = tid; i < CHUNK; i += 256) ldsSq[i] = sq2[cbase0 + i];

    // A fragments: rows rbase..rbase+15, full K=128, resident for the sweep.
    bf16x8 afrag[4];
    {
        const unsigned short* ap = f1b + (rbase + lo) * D + hi * 8;
        #pragma unroll
        for (int kk = 0; kk < 4; kk++)
            afrag[kk] = *reinterpret_cast<const bf16x8*>(ap + kk * 32);
    }

    // staging address precompute: position q -> global col c(q)
    const int sq_ = (tid >> 4);           // q within 16-position group, per it
    const int sg_ = tid & 15;             // 16B chunk index
    // per-thread byte offsets into f2b for the 4 staging iterations
    // (q = it*16 + sq_, c(q) = 4*(q&15) + (q>>4))

    // mask pointer: rows rbase+hi*4+r, cols cbase + 4*lo
    const int* simi_p = simi + (size_t)(rbase + hi * 4) * N + cbase0 + 4 * lo;

    float m[4], l[4], s[4];
    #pragma unroll
    for (int r = 0; r < 4; r++) { m[r] = -1e30f; l[r] = 0.f; s[r] = 0.f; }
    uint32 cnt = 0;

    for (int t = 0; t < NTILES; t++) {
        const int cbase = cbase0 + t * CT;

        // mask loads: 4x dwordx4, independent of LDS -> overlap with staging
        int4 msk[4];
        #pragma unroll
        for (int r = 0; r < 4; r++)
            msk[r] = *reinterpret_cast<const int4*>(simi_p + (size_t)r * N);

        __syncthreads();  // previous tile's LDS reads complete
        // stage B tile: position q holds global col c(q)
        #pragma unroll
        for (int it = 0; it < 4; it++) {
            int q = it * 16 + sq_;
            int c = 4 * (q & 15) + (q >> 4);
            const uint4 v = *reinterpret_cast<const uint4*>(f2b + (size_t)(cbase + c) * D + sg_ * 8);
            *reinterpret_cast<uint4*>(ldsB + q * D + ((sg_ ^ (q & 15)) * 8)) = v;
        }
        __syncthreads();

        // MFMA: scores for 16 rows x 64 (permuted) cols
        f32x4 acc[4];
        #pragma unroll
        for (int cf = 0; cf < 4; cf++) {
            acc[cf] = (f32x4){0.f, 0.f, 0.f, 0.f};
            const int brow = cf * 16 + lo;
            #pragma unroll
            for (int kk = 0; kk < 4; kk++) {
                int g = kk * 4 + hi;
                bf16x8 b = *reinterpret_cast<const bf16x8*>(
                    ldsB + brow * D + ((g ^ (brow & 15)) * 8));
                acc[cf] = __builtin_amdgcn_mfma_f32_16x16x32_bf16(afrag[kk], b, acc[cf], 0, 0, 0);
            }
        }

        // sq2 for this lane's 4 cols (4lo..4lo+3), component cf <-> acc[cf]
        f32x4 sqv = *reinterpret_cast<const f32x4*>(&ldsSq[t * CT + 4 * lo]);

        // logits (sq1 dropped: softmax-row-invariant): lg = 2c - sq2[col]
        float lg[4][4];
        #pragma unroll
        for (int cf = 0; cf < 4; cf++)
            #pragma unroll
            for (int r = 0; r < 4; r++)
                lg[cf][r] = 2.0f * acc[cf][r] - sqv[cf];

        // per-row tile max over 4 cf + 16 lo lanes, merge into running m
        #pragma unroll
        for (int r = 0; r < 4; r++) {
            float tm = fmaxf(fmaxf(lg[0][r], lg[1][r]), fmaxf(lg[2][r], lg[3][r]));
            #pragma unroll
            for (int off = 1; off < 16; off <<= 1)
                tm = fmaxf(tm, __shfl_xor(tm, off));
            float mn = fmaxf(m[r], tm);
            float al = __expf(m[r] - mn);
            l[r] *= al; s[r] *= al; m[r] = mn;
        }
        // accumulate exp + mask (msk[r] component cf matches acc[cf][r])
        #pragma unroll
        for (int r = 0; r < 4; r++) {
            const int mk[4] = {msk[r].x, msk[r].y, msk[r].z, msk[r].w};
            #pragma unroll
            for (int cf = 0; cf < 4; cf++) {
                float p = __expf(lg[cf][r] - m[r]);
                l[r] += p;
                if (mk[cf] == 1) s[r] += p; else cnt++;
            }
        }
        simi_p += CT;
    }

    // reduce l,s across the 16-lane lo group (m already uniform over lo)
    #pragma unroll
    for (int r = 0; r < 4; r++) {
        #pragma unroll
        for (int off = 1; off < 16; off <<= 1) {
            l[r] += __shfl_xor(l[r], off);
            s[r] += __shfl_xor(s[r], off);
        }
    }
    if (lo == 0) {
        #pragma unroll
        for (int r = 0; r < 4; r++) {
            int row = rbase + hi * 4 + r;
            int idx = chunk * N + row;
            pm[idx] = m[r]; pl[idx] = l[r]; ps[idx] = s[r];
        }
    }
    #pragma unroll
    for (int off = 1; off < 64; off <<= 1) cnt += __shfl_xor(cnt, off);
    if (lane == 0) atomicAdd(cnt_acc, cnt);
}

// Merge per-chunk (m,l,s) partials per row; accumulate sum of s/l.
__global__ void merge_kernel(const float* __restrict__ pm, const float* __restrict__ pl,
                             const float* __restrict__ ps, float* __restrict__ s_acc) {
    const int row = blockIdx.x * 256 + threadIdx.x;
    float M = -1e30f;
    #pragma unroll
    for (int k = 0; k < NCHUNK; k++) M = fmaxf(M, pm[k * N + row]);
    float L = 0.f, S = 0.f;
    #pragma unroll
    for (int k = 0; k < NCHUNK; k++) {
        float e = __expf(pm[k * N + row] - M);
        L += pl[k * N + row] * e;
        S += ps[k * N + row] * e;
    }
    float r = S / L;
    #pragma unroll
    for (int off = 32; off > 0; off >>= 1) r += __shfl_xor(r, off);
    __shared__ float red[4];
    int lane = threadIdx.x & 63, w = threadIdx.x >> 6;
    if (lane == 0) red[w] = r;
    __syncthreads();
    if (threadIdx.x == 0) atomicAdd(s_acc, red[0] + red[1] + red[2] + red[3]);
}

__global__ void final_kernel(const float* __restrict__ s_acc, const uint32* __restrict__ cnt_acc,
                             float* __restrict__ out) {
    double S = (double)s_acc[0];
    double C = (double)cnt_acc[0];
    double n = (double)N;
    out[0] = (float)((2.0 * S + C - n) / (n * n));
}

extern "C" void kernel_launch(void* const* d_in, const int* in_sizes, int n_in,
                              void* d_out, int out_size, void* d_ws, size_t ws_size,
                              hipStream_t stream) {
    const float* f1   = (const float*)d_in[0];
    const float* f2   = (const float*)d_in[1];
    const int*   simi = (const int*)d_in[2];
    float* out = (float*)d_out;
    char* ws = (char*)d_ws;

    float*  acc_s = (float*)(ws + OFF_ACC);
    uint32* acc_c = (uint32*)(ws + OFF_ACC + 4);
    float*  sq2   = (float*)(ws + OFF_SQ2);
    float*  pm    = (float*)(ws + OFF_M);
    float*  pl    = (float*)(ws + OFF_L);
    float*  ps    = (float*)(ws + OFF_S);
    unsigned short* f1b = (unsigned short*)(ws + OFF_F1);
    unsigned short* f2b = (unsigned short*)(ws + OFF_F2);

    hipMemsetAsync(ws + OFF_ACC, 0, 64, stream);
    prep_kernel<<<256, 256, 0, stream>>>(f1, f2, f1b, f2b, sq2);
    main_kernel<<<dim3(N / RT, NCHUNK), 256, 0, stream>>>(f1b, f2b, sq2, simi, pm, pl, ps, acc_c);
    merge_kernel<<<N / 256, 256, 0, stream>>>(pm, pl, ps, acc_s);
    final_kernel<<<1, 1, 0, stream>>>(acc_s, acc_c, out);
}

// Round 3
// 422.234 us; speedup vs baseline: 1.2624x; 1.2624x over previous
//
#include <hip/hip_runtime.h>
#include <hip/hip_bf16.h>
#include <stdint.h>

#define N 8192
#define D 128
#define NCHUNK 16
#define CHUNK (N / NCHUNK)      // 512 cols per chunk
#define RT 64                   // rows per block (4 waves x 16)
#define CT 64                   // cols per LDS tile
#define NTILES (CHUNK / CT)     // 8

typedef short bf16x8 __attribute__((ext_vector_type(8)));
typedef float f32x4 __attribute__((ext_vector_type(4)));
typedef unsigned int uint32;

// ---- workspace layout (bytes) ----
#define OFF_ACC   0u                         // [0] float S_sum, [4] uint32 C_count
#define OFF_SQ2   1024u                      // 8192 floats
#define OFF_M     40960u                     // NCHUNK*N floats
#define OFF_L     (OFF_M + NCHUNK * N * 4u)
#define OFF_S     (OFF_L + NCHUNK * N * 4u)
#define OFF_F1    (OFF_S + NCHUNK * N * 4u)  // feat1 bf16 (N*D ushort)
#define OFF_F2    (OFF_F1 + N * D * 2u)      // feat2 bf16

// Convert feats to bf16; compute sq2[j] = ||feat2_j||^2.
__global__ __launch_bounds__(256)
void prep_kernel(const float* __restrict__ f1, const float* __restrict__ f2,
                 unsigned short* __restrict__ f1b, unsigned short* __restrict__ f2b,
                 float* __restrict__ sq2) {
    const int w    = blockIdx.x * 4 + (threadIdx.x >> 6);  // 0..1023
    const int lane = threadIdx.x & 63;
    for (int row = w; row < N; row += 1024) {
        float a0 = f1[row * D + lane];
        float a1 = f1[row * D + 64 + lane];
        float b0 = f2[row * D + lane];
        float b1 = f2[row * D + 64 + lane];
        __hip_bfloat16 t;
        t = __float2bfloat16(a0); f1b[row * D + lane]      = *(unsigned short*)&t;
        t = __float2bfloat16(a1); f1b[row * D + 64 + lane] = *(unsigned short*)&t;
        t = __float2bfloat16(b0); f2b[row * D + lane]      = *(unsigned short*)&t;
        t = __float2bfloat16(b1); f2b[row * D + 64 + lane] = *(unsigned short*)&t;
        float ss = b0 * b0 + b1 * b1;
        #pragma unroll
        for (int off = 32; off > 0; off >>= 1) ss += __shfl_xor(ss, off);
        if (lane == 0) sq2[row] = ss;
    }
}

// Fused GEMM + online softmax + masked accumulation.
// Block = (rowtile, chunk): rows [rowtile*64, +64), cols [chunk*512, +512).
// Column permutation: LDS B-position q holds global col c(q)=4*(q&15)+(q>>4),
// so acc[cf] lane lo holds global col 4*lo+cf -> mask loads become int4.
// Softmax row-sums / maxes are permutation-invariant, so this is free.
// NOTE: no min-waves launch bound — round 2's (256,8) forced VGPR=32 and
// spilled ~400 MB/dispatch to scratch (WRITE_SIZE 0.9->208 MB). Let the
// compiler pick; pressure is reduced via bit-packed masks + in-place logits.
__global__ __launch_bounds__(256)
void main_kernel(const unsigned short* __restrict__ f1b,
                 const unsigned short* __restrict__ f2b,
                 const float* __restrict__ sq2,
                 const int* __restrict__ simi,
                 float* __restrict__ pm, float* __restrict__ pl, float* __restrict__ ps,
                 uint32* __restrict__ cnt_acc) {
    __shared__ unsigned short ldsB[CT * D];  // 16 KB, XOR-swizzled
    __shared__ float ldsSq[CHUNK];           // 2 KB

    const int tid  = threadIdx.x;
    const int wave = tid >> 6;
    const int lane = tid & 63;
    const int lo   = lane & 15;
    const int hi   = lane >> 4;

    const int rowtile = blockIdx.x;       // 0..127
    const int chunk   = blockIdx.y;       // 0..15
    const int rbase   = rowtile * RT + wave * 16;
    const int cbase0  = chunk * CHUNK;

    // stage sq2 for this chunk (covered by the first tile's __syncthreads)
    for (int i = tid; i < CHUNK; i += 256) ldsSq[i] = sq2[cbase0 + i];

    // A fragments: rows rbase..rbase+15, full K=128, resident for the sweep.
    bf16x8 afrag[4];
    {
        const unsigned short* ap = f1b + (rbase + lo) * D + hi * 8;
        #pragma unroll
        for (int kk = 0; kk < 4; kk++)
            afrag[kk] = *reinterpret_cast<const bf16x8*>(ap + kk * 32);
    }

    const int sq_ = (tid >> 4);           // staging: position within 16-group
    const int sg_ = tid & 15;             // staging: 16B chunk index

    // mask pointer: rows rbase+hi*4+r, cols cbase0 + 4*lo
    const int* simi_p = simi + (size_t)(rbase + hi * 4) * N + cbase0 + 4 * lo;

    float m[4], l[4], s[4];
    #pragma unroll
    for (int r = 0; r < 4; r++) { m[r] = -1e30f; l[r] = 0.f; s[r] = 0.f; }
    uint32 cnt = 0;

    for (int t = 0; t < NTILES; t++) {
        const int cbase = cbase0 + t * CT;

        // mask loads -> bit-pack immediately (4 held VGPRs, not 16)
        uint32 mb[4];
        #pragma unroll
        for (int r = 0; r < 4; r++) {
            int4 mk = *reinterpret_cast<const int4*>(simi_p + (size_t)r * N);
            mb[r] = (uint32)(mk.x == 1) | ((uint32)(mk.y == 1) << 1) |
                    ((uint32)(mk.z == 1) << 2) | ((uint32)(mk.w == 1) << 3);
            cnt += 4u - __popc(mb[r]);
        }

        __syncthreads();  // previous tile's LDS reads complete
        // stage B tile: position q holds global col c(q)=4*(q&15)+(q>>4)
        #pragma unroll
        for (int it = 0; it < 4; it++) {
            int q = it * 16 + sq_;
            int c = 4 * (q & 15) + (q >> 4);
            const uint4 v = *reinterpret_cast<const uint4*>(f2b + (size_t)(cbase + c) * D + sg_ * 8);
            *reinterpret_cast<uint4*>(ldsB + q * D + ((sg_ ^ (q & 15)) * 8)) = v;
        }
        __syncthreads();

        // MFMA: scores for 16 rows x 64 (permuted) cols
        f32x4 acc[4];
        #pragma unroll
        for (int cf = 0; cf < 4; cf++) {
            acc[cf] = (f32x4){0.f, 0.f, 0.f, 0.f};
            const int brow = cf * 16 + lo;
            #pragma unroll
            for (int kk = 0; kk < 4; kk++) {
                int g = kk * 4 + hi;
                bf16x8 b = *reinterpret_cast<const bf16x8*>(
                    ldsB + brow * D + ((g ^ (brow & 15)) * 8));
                acc[cf] = __builtin_amdgcn_mfma_f32_16x16x32_bf16(afrag[kk], b, acc[cf], 0, 0, 0);
            }
        }

        // sq2 for this lane's 4 cols (4lo..4lo+3); logits in-place:
        // lg = 2c - sq2[col] (row-constant sq1 dropped: softmax-invariant)
        f32x4 sqv = *reinterpret_cast<const f32x4*>(&ldsSq[t * CT + 4 * lo]);
        #pragma unroll
        for (int cf = 0; cf < 4; cf++)
            #pragma unroll
            for (int r = 0; r < 4; r++)
                acc[cf][r] = 2.0f * acc[cf][r] - sqv[cf];

        // per-row tile max over 4 cf + 16 lo lanes, merge into running m
        #pragma unroll
        for (int r = 0; r < 4; r++) {
            float tm = fmaxf(fmaxf(acc[0][r], acc[1][r]), fmaxf(acc[2][r], acc[3][r]));
            #pragma unroll
            for (int off = 1; off < 16; off <<= 1)
                tm = fmaxf(tm, __shfl_xor(tm, off));
            float mn = fmaxf(m[r], tm);
            float al = __expf(m[r] - mn);
            l[r] *= al; s[r] *= al; m[r] = mn;
        }
        // accumulate exp + mask (mb[r] bit cf matches acc[cf][r])
        #pragma unroll
        for (int r = 0; r < 4; r++)
            #pragma unroll
            for (int cf = 0; cf < 4; cf++) {
                float p = __expf(acc[cf][r] - m[r]);
                l[r] += p;
                if ((mb[r] >> cf) & 1u) s[r] += p;
            }
        simi_p += CT;
    }

    // reduce l,s across the 16-lane lo group (m already uniform over lo)
    #pragma unroll
    for (int r = 0; r < 4; r++) {
        #pragma unroll
        for (int off = 1; off < 16; off <<= 1) {
            l[r] += __shfl_xor(l[r], off);
            s[r] += __shfl_xor(s[r], off);
        }
    }
    if (lo == 0) {
        #pragma unroll
        for (int r = 0; r < 4; r++) {
            int row = rbase + hi * 4 + r;
            int idx = chunk * N + row;
            pm[idx] = m[r]; pl[idx] = l[r]; ps[idx] = s[r];
        }
    }
    #pragma unroll
    for (int off = 1; off < 64; off <<= 1) cnt += __shfl_xor(cnt, off);
    if (lane == 0) atomicAdd(cnt_acc, cnt);
}

// Merge per-chunk (m,l,s) partials per row; accumulate sum of s/l.
__global__ void merge_kernel(const float* __restrict__ pm, const float* __restrict__ pl,
                             const float* __restrict__ ps, float* __restrict__ s_acc) {
    const int row = blockIdx.x * 256 + threadIdx.x;
    float M = -1e30f;
    #pragma unroll
    for (int k = 0; k < NCHUNK; k++) M = fmaxf(M, pm[k * N + row]);
    float L = 0.f, S = 0.f;
    #pragma unroll
    for (int k = 0; k < NCHUNK; k++) {
        float e = __expf(pm[k * N + row] - M);
        L += pl[k * N + row] * e;
        S += ps[k * N + row] * e;
    }
    float r = S / L;
    #pragma unroll
    for (int off = 32; off > 0; off >>= 1) r += __shfl_xor(r, off);
    __shared__ float red[4];
    int lane = threadIdx.x & 63, w = threadIdx.x >> 6;
    if (lane == 0) red[w] = r;
    __syncthreads();
    if (threadIdx.x == 0) atomicAdd(s_acc, red[0] + red[1] + red[2] + red[3]);
}

__global__ void final_kernel(const float* __restrict__ s_acc, const uint32* __restrict__ cnt_acc,
                             float* __restrict__ out) {
    double S = (double)s_acc[0];
    double C = (double)cnt_acc[0];
    double n = (double)N;
    out[0] = (float)((2.0 * S + C - n) / (n * n));
}

extern "C" void kernel_launch(void* const* d_in, const int* in_sizes, int n_in,
                              void* d_out, int out_size, void* d_ws, size_t ws_size,
                              hipStream_t stream) {
    const float* f1   = (const float*)d_in[0];
    const float* f2   = (const float*)d_in[1];
    const int*   simi = (const int*)d_in[2];
    float* out = (float*)d_out;
    char* ws = (char*)d_ws;

    float*  acc_s = (float*)(ws + OFF_ACC);
    uint32* acc_c = (uint32*)(ws + OFF_ACC + 4);
    float*  sq2   = (float*)(ws + OFF_SQ2);
    float*  pm    = (float*)(ws + OFF_M);
    float*  pl    = (float*)(ws + OFF_L);
    float*  ps    = (float*)(ws + OFF_S);
    unsigned short* f1b = (unsigned short*)(ws + OFF_F1);
    unsigned short* f2b = (unsigned short*)(ws + OFF_F2);

    hipMemsetAsync(ws + OFF_ACC, 0, 64, stream);
    prep_kernel<<<256, 256, 0, stream>>>(f1, f2, f1b, f2b, sq2);
    main_kernel<<<dim3(N / RT, NCHUNK), 256, 0, stream>>>(f1b, f2b, sq2, simi, pm, pl, ps, acc_c);
    merge_kernel<<<N / 256, 256, 0, stream>>>(pm, pl, ps, acc_s);
    final_kernel<<<1, 1, 0, stream>>>(acc_s, acc_c, out);
}